// Round 6
// baseline (1738.339 us; speedup 1.0000x reference)
//
#include <hip/hip_runtime.h>
#include <stdint.h>

#define DGRID 128
#define D3 (DGRID * DGRID * DGRID)
#define NBATCH 2
#define NPTS 150000
#define NROWS (NBATCH * NPTS)
#define NPAD 300032            // ceil(NROWS/64)*64
#define ZROW NROWS             // dedicated all-zero row of h (sorted space)
#define NCBLK (NPAD / 128)     // 2344 conv blocks (4 waves x 32 rows)
#define NCELLS 8192            // 2 batches x 16^3 macro-cells (8^3 voxels each)
#define EPSBN 1e-4f
#define SBLK 1024

typedef __attribute__((ext_vector_type(8))) short s16x8;
typedef __attribute__((ext_vector_type(4))) float f32x4;

static __device__ __forceinline__ uint32_t f2bf_rne(float f) {
  uint32_t b = __float_as_uint(f);
  return (b + 0x7FFFu + ((b >> 16) & 1u)) >> 16;
}

static __device__ __forceinline__ f32x4 mfma16(uint4 a, uint4 b, f32x4 c) {
  return __builtin_amdgcn_mfma_f32_16x16x32_bf16(
      __builtin_bit_cast(s16x8, a), __builtin_bit_cast(s16x8, b), c, 0, 0, 0);
}

// scatter point indices into dense voxel LUT (codes unique per sample)
__global__ void k_scatter(const int* __restrict__ pos, int* __restrict__ lut) {
  int g = blockIdx.x * blockDim.x + threadIdx.x;
  if (g >= NROWS) return;
  int b = g / NPTS;
  int i = g - b * NPTS;
  int x = pos[3 * g], y = pos[3 * g + 1], z = pos[3 * g + 2];
  lut[(size_t)b * D3 + (x * DGRID + y) * DGRID + z] = i;
}

// count points per macro-cell (8^3 voxels)
__global__ void k_cellcount(const int* __restrict__ pos, int* __restrict__ cnt) {
  int g = blockIdx.x * blockDim.x + threadIdx.x;
  if (g >= NROWS) return;
  int b = g / NPTS;
  int cid = (b << 12) | ((pos[3 * g] >> 3) << 8) | ((pos[3 * g + 1] >> 3) << 4) |
            (pos[3 * g + 2] >> 3);
  atomicAdd(&cnt[cid], 1);
}

// exclusive prefix scan of NCELLS counters, single block
__global__ void k_scan(const int* __restrict__ cnt, int* __restrict__ cstart) {
  __shared__ int s[1024];
  int tid = threadIdx.x;
  int e[8];
  int sum = 0;
#pragma unroll
  for (int j = 0; j < 8; j++) {
    int v = cnt[tid * 8 + j];
    e[j] = sum;
    sum += v;
  }
  s[tid] = sum;
  __syncthreads();
  for (int off = 1; off < 1024; off <<= 1) {
    int t = (tid >= off) ? s[tid - off] : 0;
    __syncthreads();
    s[tid] += t;
    __syncthreads();
  }
  int base = tid ? s[tid - 1] : 0;
#pragma unroll
  for (int j = 0; j < 8; j++) cstart[tid * 8 + j] = base + e[j];
}

// scatter points into cell-sorted order; perm: sorted->orig, iperm: orig->sorted
__global__ void k_bucket(const int* __restrict__ pos, const int* __restrict__ cstart,
                         int* __restrict__ fill, int* __restrict__ perm,
                         int* __restrict__ iperm) {
  int g = blockIdx.x * blockDim.x + threadIdx.x;
  if (g >= NROWS) return;
  int b = g / NPTS;
  int cid = (b << 12) | ((pos[3 * g] >> 3) << 8) | ((pos[3 * g + 1] >> 3) << 4) |
            (pos[3 * g + 2] >> 3);
  int slot = cstart[cid] + atomicAdd(&fill[cid], 1);
  perm[slot] = g;
  iperm[g] = slot;
}

// sorted-space dense neighbor table; invalid/missing/pad -> ZROW
__global__ void k_nbr_s(const int* __restrict__ pos, const int* __restrict__ lut,
                        const int* __restrict__ perm, const int* __restrict__ iperm,
                        int* __restrict__ nbr) {
  int s = blockIdx.x * blockDim.x + threadIdx.x;
  if (s >= NPAD) return;
  if (s >= NROWS) {
#pragma unroll
    for (int t = 0; t < 27; ++t) nbr[(size_t)t * NPAD + s] = ZROW;
    return;
  }
  int g = perm[s];
  int b = g / NPTS;
  int x = pos[3 * g], y = pos[3 * g + 1], z = pos[3 * g + 2];
  const int* L = lut + (size_t)b * D3;
  const int* ip = iperm + (size_t)b * NPTS;
#pragma unroll
  for (int t = 0; t < 27; ++t) {
    int nx = x + t / 9 - 1;
    int ny = y + (t / 3) % 3 - 1;
    int nz = z + t % 3 - 1;
    int v = ZROW;
    if ((unsigned)nx < DGRID && (unsigned)ny < DGRID && (unsigned)nz < DGRID) {
      int n = L[(nx * DGRID + ny) * DGRID + nz];
      if (n >= 0) v = ip[n];
    }
    nbr[(size_t)t * NPAD + s] = v;
  }
}

// pack W into exact mfma_16x16x32_bf16 B-fragment layout:
// Wfrag[((cid*27+t)*2+s)*256 + nb*64 + lane]
__global__ void k_wpack(const float* __restrict__ Ws, uint4* __restrict__ Wfrag) {
  int e = blockIdx.x * 256 + threadIdx.x;
  if (e >= 4 * 27 * 512) return;
  int lane = e & 63, nb = (e >> 6) & 3, s = (e >> 8) & 1, tt = e >> 9;
  int kb = s * 32 + (lane >> 4) * 8;
  int cout = nb * 16 + (lane & 15);
  const float* src = Ws + (size_t)tt * 4096;
  uint32_t p[4];
#pragma unroll
  for (int j = 0; j < 4; ++j) {
    uint32_t lo = f2bf_rne(src[(kb + 2 * j) * 64 + cout]);
    uint32_t hi = f2bf_rne(src[(kb + 2 * j + 1) * 64 + cout]);
    p[j] = (hi << 16) | lo;
  }
  uint4 o;
  o.x = p[0]; o.y = p[1]; o.z = p[2]; o.w = p[3];
  Wfrag[e] = o;
}

// stage-1 BN stats over a f32 [NROWS][64] tensor (feats only; order-independent)
__global__ void k_stats1(const float* __restrict__ X, float* __restrict__ part) {
  __shared__ float s[512];
  int c = threadIdx.x & 63, q = threadIdx.x >> 6;
  float sm = 0.f, sq = 0.f;
  for (int r = blockIdx.x * 4 + q; r < NROWS; r += SBLK * 4) {
    float v = X[(size_t)r * 64 + c];
    sm += v;
    sq += v * v;
  }
  s[threadIdx.x] = sm;
  s[256 + threadIdx.x] = sq;
  __syncthreads();
  if (q == 0) {
    sm = s[c] + s[64 + c] + s[128 + c] + s[192 + c];
    sq = s[256 + c] + s[320 + c] + s[384 + c] + s[448 + c];
    part[blockIdx.x * 128 + c] = sm;
    part[blockIdx.x * 128 + 64 + c] = sq;
  }
}

// stage-2: reduce nblk partials -> affine (a, b') with bnrelu(x)=relu(x*a+b')
__global__ void k_stats2(const float* __restrict__ part, int nblk,
                         const float* __restrict__ gamma, const float* __restrict__ beta,
                         float* __restrict__ chanp, int cid) {
  __shared__ float s[512];
  int c = threadIdx.x & 63, q = threadIdx.x >> 6;
  float sm = 0.f, sq = 0.f;
  for (int rb = q; rb < nblk; rb += 4) {
    sm += part[rb * 128 + c];
    sq += part[rb * 128 + 64 + c];
  }
  s[threadIdx.x] = sm;
  s[256 + threadIdx.x] = sq;
  __syncthreads();
  if (q == 0) {
    sm = s[c] + s[64 + c] + s[128 + c] + s[192 + c];
    sq = s[256 + c] + s[320 + c] + s[384 + c] + s[448 + c];
    float mean = sm / (float)NROWS;
    float var = sq / (float)NROWS - mean * mean;
    float a = gamma[cid * 64 + c] * rsqrtf(var + EPSBN);
    chanp[cid * 128 + c] = a;
    chanp[cid * 128 + 64 + c] = beta[cid * 64 + c] - mean * a;
  }
}

// h[slot] = bnrelu(X[gperm ? gperm[slot] : slot]) as bf16; row ZROW = zeros
__global__ void k_hpass(const float* __restrict__ X, const float* __restrict__ chanp,
                        int cid, const int* __restrict__ gperm, uint4* __restrict__ h) {
  int g = blockIdx.x * blockDim.x + threadIdx.x;
  if (g >= (NROWS + 1) * 8) return;
  int row = g >> 3;
  if (row >= NROWS) {
    h[g] = (uint4){0u, 0u, 0u, 0u};
    return;
  }
  int src = gperm ? gperm[row] : row;
  int c0 = (g & 7) * 8;
  const float* cp = chanp + cid * 128;
  const float4 a0 = *(const float4*)(cp + c0);
  const float4 a1 = *(const float4*)(cp + c0 + 4);
  const float4 b0 = *(const float4*)(cp + 64 + c0);
  const float4 b1 = *(const float4*)(cp + 64 + c0 + 4);
  const float* Xr = X + (size_t)src * 64 + c0;
  const float4 x0 = *(const float4*)Xr;
  const float4 x1 = *(const float4*)(Xr + 4);
  float v0 = fmaxf(fmaf(x0.x, a0.x, b0.x), 0.f);
  float v1 = fmaxf(fmaf(x0.y, a0.y, b0.y), 0.f);
  float v2 = fmaxf(fmaf(x0.z, a0.z, b0.z), 0.f);
  float v3 = fmaxf(fmaf(x0.w, a0.w, b0.w), 0.f);
  float v4 = fmaxf(fmaf(x1.x, a1.x, b1.x), 0.f);
  float v5 = fmaxf(fmaf(x1.y, a1.y, b1.y), 0.f);
  float v6 = fmaxf(fmaf(x1.z, a1.z, b1.z), 0.f);
  float v7 = fmaxf(fmaf(x1.w, a1.w, b1.w), 0.f);
  uint4 o;
  o.x = (f2bf_rne(v1) << 16) | f2bf_rne(v0);
  o.y = (f2bf_rne(v3) << 16) | f2bf_rne(v2);
  o.z = (f2bf_rne(v5) << 16) | f2bf_rne(v4);
  o.w = (f2bf_rne(v7) << 16) | f2bf_rne(v6);
  h[g] = o;
}

// One tap phase: ds_read W-frags from LDS slot KS, 16 MFMAs on A-buf AC,
// then refill AC with A(T+2) (addresses NIC=ni(T+2)) and NIC with ni(T+4).
// A-refill issued AFTER the MFMAs that consume AC (reg-dep keeps order);
// the loads get ~1.3 phases of latency cover before MFMA(T+2) needs them.
#define PHASE(KS, T, AC, NIC)                                               \
  {                                                                         \
    uint4 wf[8];                                                            \
    _Pragma("unroll") for (int i = 0; i < 8; i++)                           \
        wf[i] = wlds[(KS) * 512 + i * 64 + lane];                           \
    _Pragma("unroll") for (int s = 0; s < 2; s++)                           \
      _Pragma("unroll") for (int rt = 0; rt < 2; rt++)                      \
        _Pragma("unroll") for (int nb = 0; nb < 4; nb++)                    \
          acc[rt][nb] = mfma16(AC[rt][s], wf[s * 4 + nb], acc[rt][nb]);     \
    {                                                                       \
      const uint4* hp0 = h + (size_t)NIC[0] * 8 + lkg;                      \
      const uint4* hp1 = h + (size_t)NIC[1] * 8 + lkg;                      \
      AC[0][0] = hp0[0]; AC[0][1] = hp0[4];                                 \
      AC[1][0] = hp1[0]; AC[1][1] = hp1[4];                                 \
    }                                                                       \
    int tn = (T) + 4 <= 26 ? (T) + 4 : 26;                                  \
    NIC[0] = nbp[(size_t)tn * NPAD];                                        \
    NIC[1] = nbp[(size_t)tn * NPAD + 16];                                   \
  }

// MFMA conv in sorted space: wave = 32 rows x 64 cout; dense 27 taps in 7
// groups of <=4; W staged per group in LDS (32 KB, shared by 4 waves);
// A depth-2 register ping-pong; fully coalesced epilogue (1 KB spans).
__global__ __launch_bounds__(256) void k_conv(
    const uint4* __restrict__ h, const uint4* __restrict__ Wf,
    const int* __restrict__ nbr, const float* __restrict__ res,
    const int* __restrict__ rperm, float* __restrict__ out,
    const int* __restrict__ wperm, float* __restrict__ part, int do_stats) {
  __shared__ uint4 smem4[2048];  // 32 KB: W tiles; reused as slab+sred in epilogue
  uint4* wlds = smem4;
  char* smem = (char*)smem4;
  int tid = threadIdx.x, wv = tid >> 6, lane = tid & 63;
  int tbase = (blockIdx.x * 4 + wv) * 32;
  int lrow = lane & 15, lkg = lane >> 4;

  f32x4 acc[2][4];
#pragma unroll
  for (int i = 0; i < 2; i++)
#pragma unroll
    for (int j = 0; j < 4; j++) acc[i][j] = (f32x4){0.f, 0.f, 0.f, 0.f};

  const int* nbp = nbr + tbase + lrow;
  int niE[2], niO[2];
  uint4 aE[2][2], aO[2][2];
  {
    int q0 = nbp[0], q1 = nbp[16];                       // ni(0)
    int r0 = nbp[NPAD], r1 = nbp[NPAD + 16];             // ni(1)
    niE[0] = nbp[(size_t)2 * NPAD]; niE[1] = nbp[(size_t)2 * NPAD + 16];
    niO[0] = nbp[(size_t)3 * NPAD]; niO[1] = nbp[(size_t)3 * NPAD + 16];
    const uint4* hp0 = h + (size_t)q0 * 8 + lkg;
    const uint4* hp1 = h + (size_t)q1 * 8 + lkg;
    aE[0][0] = hp0[0]; aE[0][1] = hp0[4];
    aE[1][0] = hp1[0]; aE[1][1] = hp1[4];
    const uint4* hp2 = h + (size_t)r0 * 8 + lkg;
    const uint4* hp3 = h + (size_t)r1 * 8 + lkg;
    aO[0][0] = hp2[0]; aO[0][1] = hp2[4];
    aO[1][0] = hp3[0]; aO[1][1] = hp3[4];
  }

  for (int g = 0; g < 7; g++) {
    int t0 = g * 4;
    int nt = (27 - t0 >= 4) ? 4 : 27 - t0;  // 4,4,4,4,4,4,3
    __syncthreads();  // everyone done reading previous group's W
#pragma unroll 2
    for (int c = wv; c < nt * 8; c += 4) {
      uint4 v = Wf[(size_t)t0 * 512 + c * 64 + lane];
      *(uint4*)(smem + (size_t)c * 1024 + lane * 16) = v;
    }
    __syncthreads();  // all waves' W staged
    PHASE(0, t0, aE, niE)
    if (nt > 1) PHASE(1, t0 + 1, aO, niO)
    if (nt > 2) PHASE(2, t0 + 2, aE, niE)
    if (nt > 3) PHASE(3, t0 + 3, aO, niO)
  }

  // ---- epilogue: LDS transpose -> fully coalesced res/out (1 KB spans)
  float sm4[4] = {0.f, 0.f, 0.f, 0.f}, sq4[4] = {0.f, 0.f, 0.f, 0.f};
  float* slab = (float*)smem + wv * 1088;      // per-wave [16][68]
  float* sred = (float*)(smem + 17408);        // [2][4][64]
  __syncthreads();  // W region now dead for all waves
#pragma unroll 1
  for (int rt = 0; rt < 2; rt++) {
#pragma unroll
    for (int nb = 0; nb < 4; nb++)
#pragma unroll
      for (int r = 0; r < 4; r++)
        slab[(lkg * 4 + r) * 68 + nb * 16 + lrow] = acc[rt][nb][r];
    __syncthreads();
#pragma unroll
    for (int j = 0; j < 4; j++) {
      int row = tbase + rt * 16 + j * 4 + lkg;
      if (row < NROWS) {
        float4 vv = *(float4*)&slab[(j * 4 + lkg) * 68 + lrow * 4];
        size_t cofs = (size_t)lrow * 4;
        if (res) {
          int rr = rperm ? rperm[row] : row;
          float4 rv = *(const float4*)(res + (size_t)rr * 64 + cofs);
          vv.x += rv.x; vv.y += rv.y; vv.z += rv.z; vv.w += rv.w;
        }
        int rw = wperm ? wperm[row] : row;
        *(float4*)(out + (size_t)rw * 64 + cofs) = vv;
        sm4[0] += vv.x; sq4[0] += vv.x * vv.x;
        sm4[1] += vv.y; sq4[1] += vv.y * vv.y;
        sm4[2] += vv.z; sq4[2] += vv.z * vv.z;
        sm4[3] += vv.w; sq4[3] += vv.w * vv.w;
      }
    }
    __syncthreads();
  }
  if (do_stats) {
#pragma unroll
    for (int k = 0; k < 4; k++) {
      sm4[k] += __shfl_xor(sm4[k], 16); sq4[k] += __shfl_xor(sq4[k], 16);
      sm4[k] += __shfl_xor(sm4[k], 32); sq4[k] += __shfl_xor(sq4[k], 32);
    }
    if (lane < 16) {
#pragma unroll
      for (int k = 0; k < 4; k++) {
        sred[wv * 64 + lane * 4 + k] = sm4[k];
        sred[256 + wv * 64 + lane * 4 + k] = sq4[k];
      }
    }
    __syncthreads();
    if (tid < 64) {
      float s0 = 0.f, s1 = 0.f;
#pragma unroll
      for (int w = 0; w < 4; w++) {
        s0 += sred[w * 64 + tid];
        s1 += sred[256 + w * 64 + tid];
      }
      part[blockIdx.x * 128 + tid] = s0;
      part[blockIdx.x * 128 + 64 + tid] = s1;
    }
  }
}

extern "C" void kernel_launch(void* const* d_in, const int* in_sizes, int n_in,
                              void* d_out, int out_size, void* d_ws, size_t ws_size,
                              hipStream_t stream) {
  const float* feats = (const float*)d_in[0];
  const float* Ws = (const float*)d_in[1];
  const float* gammas = (const float*)d_in[2];
  const float* betas = (const float*)d_in[3];
  const int* pos = (const int*)d_in[4];
  float* out = (float*)d_out;

  char* w = (char*)d_ws;
  auto alloc = [&](size_t b) {
    char* p = w;
    w += (b + 255) & ~(size_t)255;
    return p;
  };
  int* nbr = (int*)alloc((size_t)27 * NPAD * 4);           // 32.4 MB
  uint4* Wfrag = (uint4*)alloc((size_t)4 * 27 * 512 * 16); // 0.9 MB
  float* part = (float*)alloc((size_t)NCBLK * 128 * 4);    // 1.2 MB
  float* chanp = (float*)alloc((size_t)4 * 128 * 4);       // 2 KB
  int* perm = (int*)alloc((size_t)NPAD * 4);               // 1.2 MB
  int* iperm = (int*)alloc((size_t)NROWS * 4);             // 1.2 MB
  int* ccnt = (int*)alloc((size_t)NCELLS * 4);             // 32 KB
  int* cfill = (int*)alloc((size_t)NCELLS * 4);            // 32 KB
  int* cstart = (int*)alloc((size_t)NCELLS * 4);           // 32 KB
  uint4* h = (uint4*)alloc((size_t)NPAD * 128);            // 38.4 MB
  float* xbuf = (float*)alloc((size_t)NROWS * 64 * 4);     // 76.8 MB
  char* reg0 = alloc((size_t)NROWS * 64 * 4);              // 76.8 MB
  float* cbuf = (float*)reg0;
  int* lut = (int*)reg0;  // lut (16.8 MB) dead before cbuf first written

  hipMemsetAsync(lut, 0xFF, (size_t)NBATCH * D3 * 4, stream);
  hipMemsetAsync(ccnt, 0, (size_t)NCELLS * 8, stream);  // ccnt + cfill (adjacent)
  int gpts = (NROWS + 255) / 256;
  k_scatter<<<gpts, 256, 0, stream>>>(pos, lut);
  k_cellcount<<<gpts, 256, 0, stream>>>(pos, ccnt);
  k_scan<<<1, 1024, 0, stream>>>(ccnt, cstart);
  k_bucket<<<gpts, 256, 0, stream>>>(pos, cstart, cfill, perm, iperm);
  k_nbr_s<<<NPAD / 256, 256, 0, stream>>>(pos, lut, perm, iperm, nbr);
  k_wpack<<<216, 256, 0, stream>>>(Ws, Wfrag);

  k_stats1<<<SBLK, 256, 0, stream>>>(feats, part);
  k_stats2<<<1, 256, 0, stream>>>(part, SBLK, gammas, betas, chanp, 0);
  k_hpass<<<9376, 256, 0, stream>>>(feats, chanp, 0, perm, h);
  k_conv<<<NCBLK, 256, 0, stream>>>(h, Wfrag + 0 * 27 * 512, nbr, nullptr, nullptr,
                                    cbuf, nullptr, part, 1);

  k_stats2<<<1, 256, 0, stream>>>(part, NCBLK, gammas, betas, chanp, 1);
  k_hpass<<<9376, 256, 0, stream>>>(cbuf, chanp, 1, nullptr, h);
  k_conv<<<NCBLK, 256, 0, stream>>>(h, Wfrag + 1 * 27 * 512, nbr, feats, perm,
                                    xbuf, nullptr, part, 1);

  k_stats2<<<1, 256, 0, stream>>>(part, NCBLK, gammas, betas, chanp, 2);
  k_hpass<<<9376, 256, 0, stream>>>(xbuf, chanp, 2, nullptr, h);
  k_conv<<<NCBLK, 256, 0, stream>>>(h, Wfrag + 2 * 27 * 512, nbr, nullptr, nullptr,
                                    cbuf, nullptr, part, 1);

  k_stats2<<<1, 256, 0, stream>>>(part, NCBLK, gammas, betas, chanp, 3);
  k_hpass<<<9376, 256, 0, stream>>>(cbuf, chanp, 3, nullptr, h);
  k_conv<<<NCBLK, 256, 0, stream>>>(h, Wfrag + 3 * 27 * 512, nbr, xbuf, nullptr,
                                    out, perm, part, 0);
}

// Round 7
// 1379.709 us; speedup vs baseline: 1.2599x; 1.2599x over previous
//
#include <hip/hip_runtime.h>
#include <stdint.h>

#define DGRID 128
#define D3 (DGRID * DGRID * DGRID)
#define NBATCH 2
#define NPTS 150000
#define NROWS (NBATCH * NPTS)
#define NPAD 300032            // ceil(NROWS/64)*64
#define ZROW NROWS             // dedicated all-zero row of h (sorted space)
#define NCBLK (NPAD / 128)     // 2344 conv blocks (4 waves x 32 rows)
#define NCELLS 8192            // 2 batches x 16^3 macro-cells (8^3 voxels each)
#define EPSBN 1e-4f
#define SBLK 1024

typedef __attribute__((ext_vector_type(8))) short s16x8;
typedef __attribute__((ext_vector_type(4))) float f32x4;

#define VMW(n) asm volatile("s_waitcnt vmcnt(" #n ")" ::: "memory")
#define SB0() __builtin_amdgcn_sched_barrier(0)

static __device__ __forceinline__ uint32_t f2bf_rne(float f) {
  uint32_t b = __float_as_uint(f);
  return (b + 0x7FFFu + ((b >> 16) & 1u)) >> 16;
}

static __device__ __forceinline__ f32x4 mfma16(uint4 a, uint4 b, f32x4 c) {
  return __builtin_amdgcn_mfma_f32_16x16x32_bf16(
      __builtin_bit_cast(s16x8, a), __builtin_bit_cast(s16x8, b), c, 0, 0, 0);
}

// global->LDS direct DMA, 16B/lane. LDS dest = wave-uniform base + lane*16;
// global src is PER-LANE (gather). Completion tracked by vmcnt.
static __device__ __forceinline__ void gll16(const void* g, void* l) {
  __builtin_amdgcn_global_load_lds(
      (const __attribute__((address_space(1))) void*)g,
      (__attribute__((address_space(3))) void*)l, 16, 0, 0);
}

// scatter point indices into dense voxel LUT (codes unique per sample)
__global__ void k_scatter(const int* __restrict__ pos, int* __restrict__ lut) {
  int g = blockIdx.x * blockDim.x + threadIdx.x;
  if (g >= NROWS) return;
  int b = g / NPTS;
  int i = g - b * NPTS;
  int x = pos[3 * g], y = pos[3 * g + 1], z = pos[3 * g + 2];
  lut[(size_t)b * D3 + (x * DGRID + y) * DGRID + z] = i;
}

// count points per macro-cell (8^3 voxels)
__global__ void k_cellcount(const int* __restrict__ pos, int* __restrict__ cnt) {
  int g = blockIdx.x * blockDim.x + threadIdx.x;
  if (g >= NROWS) return;
  int b = g / NPTS;
  int cid = (b << 12) | ((pos[3 * g] >> 3) << 8) | ((pos[3 * g + 1] >> 3) << 4) |
            (pos[3 * g + 2] >> 3);
  atomicAdd(&cnt[cid], 1);
}

// exclusive prefix scan of NCELLS counters, single block
__global__ void k_scan(const int* __restrict__ cnt, int* __restrict__ cstart) {
  __shared__ int s[1024];
  int tid = threadIdx.x;
  int e[8];
  int sum = 0;
#pragma unroll
  for (int j = 0; j < 8; j++) {
    int v = cnt[tid * 8 + j];
    e[j] = sum;
    sum += v;
  }
  s[tid] = sum;
  __syncthreads();
  for (int off = 1; off < 1024; off <<= 1) {
    int t = (tid >= off) ? s[tid - off] : 0;
    __syncthreads();
    s[tid] += t;
    __syncthreads();
  }
  int base = tid ? s[tid - 1] : 0;
#pragma unroll
  for (int j = 0; j < 8; j++) cstart[tid * 8 + j] = base + e[j];
}

// scatter points into cell-sorted order; perm: sorted->orig, iperm: orig->sorted
__global__ void k_bucket(const int* __restrict__ pos, const int* __restrict__ cstart,
                         int* __restrict__ fill, int* __restrict__ perm,
                         int* __restrict__ iperm) {
  int g = blockIdx.x * blockDim.x + threadIdx.x;
  if (g >= NROWS) return;
  int b = g / NPTS;
  int cid = (b << 12) | ((pos[3 * g] >> 3) << 8) | ((pos[3 * g + 1] >> 3) << 4) |
            (pos[3 * g + 2] >> 3);
  int slot = cstart[cid] + atomicAdd(&fill[cid], 1);
  perm[slot] = g;
  iperm[g] = slot;
}

// sorted-space dense neighbor table; invalid/missing/pad -> ZROW
__global__ void k_nbr_s(const int* __restrict__ pos, const int* __restrict__ lut,
                        const int* __restrict__ perm, const int* __restrict__ iperm,
                        int* __restrict__ nbr) {
  int s = blockIdx.x * blockDim.x + threadIdx.x;
  if (s >= NPAD) return;
  if (s >= NROWS) {
#pragma unroll
    for (int t = 0; t < 27; ++t) nbr[(size_t)t * NPAD + s] = ZROW;
    return;
  }
  int g = perm[s];
  int b = g / NPTS;
  int x = pos[3 * g], y = pos[3 * g + 1], z = pos[3 * g + 2];
  const int* L = lut + (size_t)b * D3;
  const int* ip = iperm + (size_t)b * NPTS;
#pragma unroll
  for (int t = 0; t < 27; ++t) {
    int nx = x + t / 9 - 1;
    int ny = y + (t / 3) % 3 - 1;
    int nz = z + t % 3 - 1;
    int v = ZROW;
    if ((unsigned)nx < DGRID && (unsigned)ny < DGRID && (unsigned)nz < DGRID) {
      int n = L[(nx * DGRID + ny) * DGRID + nz];
      if (n >= 0) v = ip[n];
    }
    nbr[(size_t)t * NPAD + s] = v;
  }
}

// pack W into exact mfma_16x16x32_bf16 B-fragment layout:
// Wfrag[((cid*27+t)*2+s)*256 + nb*64 + lane]
__global__ void k_wpack(const float* __restrict__ Ws, uint4* __restrict__ Wfrag) {
  int e = blockIdx.x * 256 + threadIdx.x;
  if (e >= 4 * 27 * 512) return;
  int lane = e & 63, nb = (e >> 6) & 3, s = (e >> 8) & 1, tt = e >> 9;
  int kb = s * 32 + (lane >> 4) * 8;
  int cout = nb * 16 + (lane & 15);
  const float* src = Ws + (size_t)tt * 4096;
  uint32_t p[4];
#pragma unroll
  for (int j = 0; j < 4; ++j) {
    uint32_t lo = f2bf_rne(src[(kb + 2 * j) * 64 + cout]);
    uint32_t hi = f2bf_rne(src[(kb + 2 * j + 1) * 64 + cout]);
    p[j] = (hi << 16) | lo;
  }
  uint4 o;
  o.x = p[0]; o.y = p[1]; o.z = p[2]; o.w = p[3];
  Wfrag[e] = o;
}

// stage-1 BN stats over a f32 [NROWS][64] tensor (feats only; order-independent)
__global__ void k_stats1(const float* __restrict__ X, float* __restrict__ part) {
  __shared__ float s[512];
  int c = threadIdx.x & 63, q = threadIdx.x >> 6;
  float sm = 0.f, sq = 0.f;
  for (int r = blockIdx.x * 4 + q; r < NROWS; r += SBLK * 4) {
    float v = X[(size_t)r * 64 + c];
    sm += v;
    sq += v * v;
  }
  s[threadIdx.x] = sm;
  s[256 + threadIdx.x] = sq;
  __syncthreads();
  if (q == 0) {
    sm = s[c] + s[64 + c] + s[128 + c] + s[192 + c];
    sq = s[256 + c] + s[320 + c] + s[384 + c] + s[448 + c];
    part[blockIdx.x * 128 + c] = sm;
    part[blockIdx.x * 128 + 64 + c] = sq;
  }
}

// stage-2: reduce nblk partials -> affine (a, b') with bnrelu(x)=relu(x*a+b')
__global__ void k_stats2(const float* __restrict__ part, int nblk,
                         const float* __restrict__ gamma, const float* __restrict__ beta,
                         float* __restrict__ chanp, int cid) {
  __shared__ float s[512];
  int c = threadIdx.x & 63, q = threadIdx.x >> 6;
  float sm = 0.f, sq = 0.f;
  for (int rb = q; rb < nblk; rb += 4) {
    sm += part[rb * 128 + c];
    sq += part[rb * 128 + 64 + c];
  }
  s[threadIdx.x] = sm;
  s[256 + threadIdx.x] = sq;
  __syncthreads();
  if (q == 0) {
    sm = s[c] + s[64 + c] + s[128 + c] + s[192 + c];
    sq = s[256 + c] + s[320 + c] + s[384 + c] + s[448 + c];
    float mean = sm / (float)NROWS;
    float var = sq / (float)NROWS - mean * mean;
    float a = gamma[cid * 64 + c] * rsqrtf(var + EPSBN);
    chanp[cid * 128 + c] = a;
    chanp[cid * 128 + 64 + c] = beta[cid * 64 + c] - mean * a;
  }
}

// h[slot] = bnrelu(X[gperm ? gperm[slot] : slot]) as bf16; row ZROW = zeros
__global__ void k_hpass(const float* __restrict__ X, const float* __restrict__ chanp,
                        int cid, const int* __restrict__ gperm, uint4* __restrict__ h) {
  int g = blockIdx.x * blockDim.x + threadIdx.x;
  if (g >= (NROWS + 1) * 8) return;
  int row = g >> 3;
  if (row >= NROWS) {
    h[g] = (uint4){0u, 0u, 0u, 0u};
    return;
  }
  int src = gperm ? gperm[row] : row;
  int c0 = (g & 7) * 8;
  const float* cp = chanp + cid * 128;
  const float4 a0 = *(const float4*)(cp + c0);
  const float4 a1 = *(const float4*)(cp + c0 + 4);
  const float4 b0 = *(const float4*)(cp + 64 + c0);
  const float4 b1 = *(const float4*)(cp + 64 + c0 + 4);
  const float* Xr = X + (size_t)src * 64 + c0;
  const float4 x0 = *(const float4*)Xr;
  const float4 x1 = *(const float4*)(Xr + 4);
  float v0 = fmaxf(fmaf(x0.x, a0.x, b0.x), 0.f);
  float v1 = fmaxf(fmaf(x0.y, a0.y, b0.y), 0.f);
  float v2 = fmaxf(fmaf(x0.z, a0.z, b0.z), 0.f);
  float v3 = fmaxf(fmaf(x0.w, a0.w, b0.w), 0.f);
  float v4 = fmaxf(fmaf(x1.x, a1.x, b1.x), 0.f);
  float v5 = fmaxf(fmaf(x1.y, a1.y, b1.y), 0.f);
  float v6 = fmaxf(fmaf(x1.z, a1.z, b1.z), 0.f);
  float v7 = fmaxf(fmaf(x1.w, a1.w, b1.w), 0.f);
  uint4 o;
  o.x = (f2bf_rne(v1) << 16) | f2bf_rne(v0);
  o.y = (f2bf_rne(v3) << 16) | f2bf_rne(v2);
  o.z = (f2bf_rne(v5) << 16) | f2bf_rne(v4);
  o.w = (f2bf_rne(v7) << 16) | f2bf_rne(v6);
  h[g] = o;
}

// MFMA conv, LDS-pipelined (m201 pattern): wave = 32 rows x 64 cout, dense 27
// taps. A gathered to per-wave LDS dbuf via global_load_lds (per-lane src);
// W staged to shared LDS dbuf one tap ahead; ni loaded via inline-asm.
// Per-phase FIFO [W2, ni2, A4] -> counted vmcnt(4)/vmcnt(6), raw s_barrier.
__global__ __launch_bounds__(256, 3) void k_conv(
    const uint4* __restrict__ h, const uint4* __restrict__ Wf,
    const int* __restrict__ nbr, const float* __restrict__ res,
    const int* __restrict__ rperm, float* __restrict__ out,
    const int* __restrict__ wperm, float* __restrict__ part, int do_stats) {
  __shared__ char smem[49152];  // [0,16K) W dbuf; [16K,48K) A dbuf 8K/wave
  int tid = threadIdx.x, wv = tid >> 6, lane = tid & 63;
  int tbase = (blockIdx.x * 4 + wv) * 32;
  int lrow = lane & 15, lkg = lane >> 4;

  f32x4 acc[2][4];
#pragma unroll
  for (int i = 0; i < 2; i++)
#pragma unroll
    for (int j = 0; j < 4; j++) acc[i][j] = (f32x4){0.f, 0.f, 0.f, 0.f};

  char* Wl = smem;
  char* Al = smem + 16384 + wv * 8192;
  const char* hb = (const char*)h;
  const int* nbp = nbr + tbase + lrow;

  // --- prologue: W(0); ni(0),ni(1); A(0)
  {
    const uint4* s0 = Wf + (wv * 2 + 0) * 64 + lane;
    const uint4* s1 = Wf + (wv * 2 + 1) * 64 + lane;
    gll16(s0, Wl + (wv * 2 + 0) * 1024);
    gll16(s1, Wl + (wv * 2 + 1) * 1024);
  }
  SB0();
  int ni0[2], ni1[2];
  {
    const int* p0 = nbp;
    const int* p1 = nbp + 16;
    asm volatile("global_load_dword %0, %2, off\n\tglobal_load_dword %1, %3, off"
                 : "=&v"(ni0[0]), "=&v"(ni0[1]) : "v"(p0), "v"(p1));
    const int* p2 = nbp + NPAD;
    const int* p3 = nbp + NPAD + 16;
    asm volatile("global_load_dword %0, %2, off\n\tglobal_load_dword %1, %3, off"
                 : "=&v"(ni1[0]), "=&v"(ni1[1]) : "v"(p2), "v"(p3));
  }
  VMW(2);  // W(0)+ni(0) done; ni(1) in flight
  SB0();
  {
    const char* r0 = hb + (size_t)ni0[0] * 128 + lkg * 16;
    const char* r1 = hb + (size_t)ni0[1] * 128 + lkg * 16;
    gll16(r0, Al);
    gll16(r0 + 64, Al + 1024);
    gll16(r1, Al + 2048);
    gll16(r1 + 64, Al + 3072);
  }
  // FIFO invariant entering loop: [ni(t+1) x2, A(t) x4]

#pragma unroll 1
  for (int t = 0; t < 27; ++t) {
    __builtin_amdgcn_s_barrier();  // all waves' W(t) landed (drained last phase)
    int sl = (t + 1) & 1;
    {  // stage W(t+1) into slot sl (holds dead W(t-1))
      int tw = t + 1 <= 26 ? t + 1 : 26;
      const uint4* s0 = Wf + (size_t)tw * 512 + (wv * 2 + 0) * 64 + lane;
      const uint4* s1 = Wf + (size_t)tw * 512 + (wv * 2 + 1) * 64 + lane;
      gll16(s0, Wl + sl * 8192 + (wv * 2 + 0) * 1024);
      gll16(s1, Wl + sl * 8192 + (wv * 2 + 1) * 1024);
    }
    SB0();  // pin W issues oldest-in-phase (vmcnt(6) below targets them)
    int niN[2];
    {  // ni(t+2) via asm (keeps compiler waitcnt pass out of the loop)
      int tn = t + 2 <= 26 ? t + 2 : 26;
      const int* p0 = nbp + (size_t)tn * NPAD;
      const int* p1 = p0 + 16;
      asm volatile("global_load_dword %0, %2, off\n\tglobal_load_dword %1, %3, off"
                   : "=&v"(niN[0]), "=&v"(niN[1]) : "v"(p0), "v"(p1));
    }
    VMW(4);  // everything of phase t-1 (A(t), ni(t+1)) done
    SB0();
    {  // gather A(t+1) into per-wave slot sl
      const char* r0 = hb + (size_t)ni1[0] * 128 + lkg * 16;
      const char* r1 = hb + (size_t)ni1[1] * 128 + lkg * 16;
      gll16(r0, Al + sl * 4096);
      gll16(r0 + 64, Al + sl * 4096 + 1024);
      gll16(r1, Al + sl * 4096 + 2048);
      gll16(r1 + 64, Al + sl * 4096 + 3072);
    }
    ni1[0] = niN[0];
    ni1[1] = niN[1];
    {  // MFMA(t): A-frag read is identity ds_read_b128 at lane*16
      const uint4* wl = (const uint4*)(Wl + (t & 1) * 8192);
      const uint4* al = (const uint4*)(Al + (t & 1) * 4096);
      uint4 af[2][2];
      af[0][0] = al[lane];
      af[0][1] = al[64 + lane];
      af[1][0] = al[128 + lane];
      af[1][1] = al[192 + lane];
      uint4 wf[8];
#pragma unroll
      for (int i = 0; i < 8; i++) wf[i] = wl[i * 64 + lane];
#pragma unroll
      for (int s = 0; s < 2; s++)
#pragma unroll
        for (int rt = 0; rt < 2; rt++)
#pragma unroll
          for (int nb = 0; nb < 4; nb++)
            acc[rt][nb] = mfma16(af[rt][s], wf[s * 4 + nb], acc[rt][nb]);
    }
    VMW(6);  // W(t+1) landed (mine) before next barrier's handoff
  }

  // ---- epilogue: drain DMA, then LDS transpose -> coalesced res/out + stats
  VMW(0);
  __syncthreads();
  float sm4[4] = {0.f, 0.f, 0.f, 0.f}, sq4[4] = {0.f, 0.f, 0.f, 0.f};
  float* slab = (float*)smem + wv * 1088;  // per-wave [16][68]
  float* sred = (float*)(smem + 17408);    // [2][4][64]
#pragma unroll 1
  for (int rt = 0; rt < 2; rt++) {
#pragma unroll
    for (int nb = 0; nb < 4; nb++)
#pragma unroll
      for (int r = 0; r < 4; r++)
        slab[(lkg * 4 + r) * 68 + nb * 16 + lrow] = acc[rt][nb][r];
    __syncthreads();
#pragma unroll
    for (int j = 0; j < 4; j++) {
      int row = tbase + rt * 16 + j * 4 + lkg;
      if (row < NROWS) {
        float4 vv = *(float4*)&slab[(j * 4 + lkg) * 68 + lrow * 4];
        size_t cofs = (size_t)lrow * 4;
        if (res) {
          int rr = rperm ? rperm[row] : row;
          float4 rv = *(const float4*)(res + (size_t)rr * 64 + cofs);
          vv.x += rv.x; vv.y += rv.y; vv.z += rv.z; vv.w += rv.w;
        }
        int rw = wperm ? wperm[row] : row;
        *(float4*)(out + (size_t)rw * 64 + cofs) = vv;
        sm4[0] += vv.x; sq4[0] += vv.x * vv.x;
        sm4[1] += vv.y; sq4[1] += vv.y * vv.y;
        sm4[2] += vv.z; sq4[2] += vv.z * vv.z;
        sm4[3] += vv.w; sq4[3] += vv.w * vv.w;
      }
    }
    __syncthreads();
  }
  if (do_stats) {
#pragma unroll
    for (int k = 0; k < 4; k++) {
      sm4[k] += __shfl_xor(sm4[k], 16); sq4[k] += __shfl_xor(sq4[k], 16);
      sm4[k] += __shfl_xor(sm4[k], 32); sq4[k] += __shfl_xor(sq4[k], 32);
    }
    if (lane < 16) {
#pragma unroll
      for (int k = 0; k < 4; k++) {
        sred[wv * 64 + lane * 4 + k] = sm4[k];
        sred[256 + wv * 64 + lane * 4 + k] = sq4[k];
      }
    }
    __syncthreads();
    if (tid < 64) {
      float s0 = 0.f, s1 = 0.f;
#pragma unroll
      for (int w = 0; w < 4; w++) {
        s0 += sred[w * 64 + tid];
        s1 += sred[256 + w * 64 + tid];
      }
      part[blockIdx.x * 128 + tid] = s0;
      part[blockIdx.x * 128 + 64 + tid] = s1;
    }
  }
}

extern "C" void kernel_launch(void* const* d_in, const int* in_sizes, int n_in,
                              void* d_out, int out_size, void* d_ws, size_t ws_size,
                              hipStream_t stream) {
  const float* feats = (const float*)d_in[0];
  const float* Ws = (const float*)d_in[1];
  const float* gammas = (const float*)d_in[2];
  const float* betas = (const float*)d_in[3];
  const int* pos = (const int*)d_in[4];
  float* out = (float*)d_out;

  char* w = (char*)d_ws;
  auto alloc = [&](size_t b) {
    char* p = w;
    w += (b + 255) & ~(size_t)255;
    return p;
  };
  int* nbr = (int*)alloc((size_t)27 * NPAD * 4);           // 32.4 MB
  uint4* Wfrag = (uint4*)alloc((size_t)4 * 27 * 512 * 16); // 0.9 MB
  float* part = (float*)alloc((size_t)NCBLK * 128 * 4);    // 1.2 MB
  float* chanp = (float*)alloc((size_t)4 * 128 * 4);       // 2 KB
  int* perm = (int*)alloc((size_t)NPAD * 4);               // 1.2 MB
  int* iperm = (int*)alloc((size_t)NROWS * 4);             // 1.2 MB
  int* ccnt = (int*)alloc((size_t)NCELLS * 4);             // 32 KB
  int* cfill = (int*)alloc((size_t)NCELLS * 4);            // 32 KB
  int* cstart = (int*)alloc((size_t)NCELLS * 4);           // 32 KB
  uint4* h = (uint4*)alloc((size_t)NPAD * 128);            // 38.4 MB
  float* xbuf = (float*)alloc((size_t)NROWS * 64 * 4);     // 76.8 MB
  char* reg0 = alloc((size_t)NROWS * 64 * 4);              // 76.8 MB
  float* cbuf = (float*)reg0;
  int* lut = (int*)reg0;  // lut (16.8 MB) dead before cbuf first written

  hipMemsetAsync(lut, 0xFF, (size_t)NBATCH * D3 * 4, stream);
  hipMemsetAsync(ccnt, 0, (size_t)NCELLS * 8, stream);  // ccnt + cfill (adjacent)
  int gpts = (NROWS + 255) / 256;
  k_scatter<<<gpts, 256, 0, stream>>>(pos, lut);
  k_cellcount<<<gpts, 256, 0, stream>>>(pos, ccnt);
  k_scan<<<1, 1024, 0, stream>>>(ccnt, cstart);
  k_bucket<<<gpts, 256, 0, stream>>>(pos, cstart, cfill, perm, iperm);
  k_nbr_s<<<NPAD / 256, 256, 0, stream>>>(pos, lut, perm, iperm, nbr);
  k_wpack<<<216, 256, 0, stream>>>(Ws, Wfrag);

  k_stats1<<<SBLK, 256, 0, stream>>>(feats, part);
  k_stats2<<<1, 256, 0, stream>>>(part, SBLK, gammas, betas, chanp, 0);
  k_hpass<<<9376, 256, 0, stream>>>(feats, chanp, 0, perm, h);
  k_conv<<<NCBLK, 256, 0, stream>>>(h, Wfrag + 0 * 27 * 512, nbr, nullptr, nullptr,
                                    cbuf, nullptr, part, 1);

  k_stats2<<<1, 256, 0, stream>>>(part, NCBLK, gammas, betas, chanp, 1);
  k_hpass<<<9376, 256, 0, stream>>>(cbuf, chanp, 1, nullptr, h);
  k_conv<<<NCBLK, 256, 0, stream>>>(h, Wfrag + 1 * 27 * 512, nbr, feats, perm,
                                    xbuf, nullptr, part, 1);

  k_stats2<<<1, 256, 0, stream>>>(part, NCBLK, gammas, betas, chanp, 2);
  k_hpass<<<9376, 256, 0, stream>>>(xbuf, chanp, 2, nullptr, h);
  k_conv<<<NCBLK, 256, 0, stream>>>(h, Wfrag + 2 * 27 * 512, nbr, nullptr, nullptr,
                                    cbuf, nullptr, part, 1);

  k_stats2<<<1, 256, 0, stream>>>(part, NCBLK, gammas, betas, chanp, 3);
  k_hpass<<<9376, 256, 0, stream>>>(cbuf, chanp, 3, nullptr, h);
  k_conv<<<NCBLK, 256, 0, stream>>>(h, Wfrag + 3 * 27 * 512, nbr, xbuf, nullptr,
                                    out, perm, part, 0);
}

// Round 9
// 1285.247 us; speedup vs baseline: 1.3525x; 1.0735x over previous
//
#include <hip/hip_runtime.h>
#include <stdint.h>

#define DGRID 128
#define D3 (DGRID * DGRID * DGRID)
#define NBATCH 2
#define NPTS 150000
#define NROWS (NBATCH * NPTS)
#define NPAD 300032            // ceil(NROWS/64)*64
#define ZROW NROWS             // dedicated all-zero row (sorted space)
#define NCBLK (NPAD / 128)     // 2344 conv blocks (4 waves x 32 rows); %8==0
#define NCELLS 8192            // 2 batches x 16^3 macro-cells (8^3 voxels each)
#define EPSBN 1e-4f

typedef __attribute__((ext_vector_type(8))) short s16x8;
typedef __attribute__((ext_vector_type(4))) float f32x4;

static __device__ __forceinline__ uint32_t f2bf_rne(float f) {
  uint32_t b = __float_as_uint(f);
  return (b + 0x7FFFu + ((b >> 16) & 1u)) >> 16;
}

static __device__ __forceinline__ uint32_t pkbf(float lo, float hi) {
  uint32_t r;
  asm("v_cvt_pk_bf16_f32 %0, %1, %2" : "=v"(r) : "v"(lo), "v"(hi));
  return r;
}

static __device__ __forceinline__ f32x4 mfma16(uint4 a, uint4 b, f32x4 c) {
  return __builtin_amdgcn_mfma_f32_16x16x32_bf16(
      __builtin_bit_cast(s16x8, a), __builtin_bit_cast(s16x8, b), c, 0, 0, 0);
}

// fused BN+ReLU on a gathered A-fragment (8 bf16 ch), invalid rows -> 0
static __device__ __forceinline__ uint4 bnrelu_frag(uint4 u, float4 aL, float4 aH,
                                                    float4 bL, float4 bH, bool vld) {
  float y0, y1;
  uint4 o;
  y0 = fmaxf(fmaf(__uint_as_float(u.x << 16), aL.x, bL.x), 0.f);
  y1 = fmaxf(fmaf(__uint_as_float(u.x & 0xFFFF0000u), aL.y, bL.y), 0.f);
  o.x = pkbf(y0, y1);
  y0 = fmaxf(fmaf(__uint_as_float(u.y << 16), aL.z, bL.z), 0.f);
  y1 = fmaxf(fmaf(__uint_as_float(u.y & 0xFFFF0000u), aL.w, bL.w), 0.f);
  o.y = pkbf(y0, y1);
  y0 = fmaxf(fmaf(__uint_as_float(u.z << 16), aH.x, bH.x), 0.f);
  y1 = fmaxf(fmaf(__uint_as_float(u.z & 0xFFFF0000u), aH.y, bH.y), 0.f);
  o.z = pkbf(y0, y1);
  y0 = fmaxf(fmaf(__uint_as_float(u.w << 16), aH.z, bH.z), 0.f);
  y1 = fmaxf(fmaf(__uint_as_float(u.w & 0xFFFF0000u), aH.w, bH.w), 0.f);
  o.w = pkbf(y0, y1);
  if (!vld) o = (uint4){0u, 0u, 0u, 0u};
  return o;
}

// ---------- geometry prep (unchanged from r5) ----------
__global__ void k_scatter(const int* __restrict__ pos, int* __restrict__ lut) {
  int g = blockIdx.x * blockDim.x + threadIdx.x;
  if (g >= NROWS) return;
  int b = g / NPTS;
  int i = g - b * NPTS;
  lut[(size_t)b * D3 + (pos[3 * g] * DGRID + pos[3 * g + 1]) * DGRID + pos[3 * g + 2]] = i;
}

__global__ void k_cellcount(const int* __restrict__ pos, int* __restrict__ cnt) {
  int g = blockIdx.x * blockDim.x + threadIdx.x;
  if (g >= NROWS) return;
  int b = g / NPTS;
  int cid = (b << 12) | ((pos[3 * g] >> 3) << 8) | ((pos[3 * g + 1] >> 3) << 4) |
            (pos[3 * g + 2] >> 3);
  atomicAdd(&cnt[cid], 1);
}

__global__ void k_scan(const int* __restrict__ cnt, int* __restrict__ cstart) {
  __shared__ int s[1024];
  int tid = threadIdx.x;
  int e[8];
  int sum = 0;
#pragma unroll
  for (int j = 0; j < 8; j++) {
    int v = cnt[tid * 8 + j];
    e[j] = sum;
    sum += v;
  }
  s[tid] = sum;
  __syncthreads();
  for (int off = 1; off < 1024; off <<= 1) {
    int t = (tid >= off) ? s[tid - off] : 0;
    __syncthreads();
    s[tid] += t;
    __syncthreads();
  }
  int base = tid ? s[tid - 1] : 0;
#pragma unroll
  for (int j = 0; j < 8; j++) cstart[tid * 8 + j] = base + e[j];
}

__global__ void k_bucket(const int* __restrict__ pos, const int* __restrict__ cstart,
                         int* __restrict__ fill, int* __restrict__ perm,
                         int* __restrict__ iperm) {
  int g = blockIdx.x * blockDim.x + threadIdx.x;
  if (g >= NROWS) return;
  int b = g / NPTS;
  int cid = (b << 12) | ((pos[3 * g] >> 3) << 8) | ((pos[3 * g + 1] >> 3) << 4) |
            (pos[3 * g + 2] >> 3);
  int slot = cstart[cid] + atomicAdd(&fill[cid], 1);
  perm[slot] = g;
  iperm[g] = slot;
}

__global__ void k_nbr_s(const int* __restrict__ pos, const int* __restrict__ lut,
                        const int* __restrict__ perm, const int* __restrict__ iperm,
                        int* __restrict__ nbr) {
  int s = blockIdx.x * blockDim.x + threadIdx.x;
  if (s >= NPAD) return;
  if (s >= NROWS) {
#pragma unroll
    for (int t = 0; t < 27; ++t) nbr[(size_t)t * NPAD + s] = ZROW;
    return;
  }
  int g = perm[s];
  int b = g / NPTS;
  int x = pos[3 * g], y = pos[3 * g + 1], z = pos[3 * g + 2];
  const int* L = lut + (size_t)b * D3;
  const int* ip = iperm + (size_t)b * NPTS;
#pragma unroll
  for (int t = 0; t < 27; ++t) {
    int nx = x + t / 9 - 1;
    int ny = y + (t / 3) % 3 - 1;
    int nz = z + t % 3 - 1;
    int v = ZROW;
    if ((unsigned)nx < DGRID && (unsigned)ny < DGRID && (unsigned)nz < DGRID) {
      int n = L[(nx * DGRID + ny) * DGRID + nz];
      if (n >= 0) v = ip[n];
    }
    nbr[(size_t)t * NPAD + s] = v;
  }
}

__global__ void k_wpack(const float* __restrict__ Ws, uint4* __restrict__ Wfrag) {
  int e = blockIdx.x * 256 + threadIdx.x;
  if (e >= 4 * 27 * 512) return;
  int lane = e & 63, nb = (e >> 6) & 3, s = (e >> 8) & 1, tt = e >> 9;
  int kb = s * 32 + (lane >> 4) * 8;
  int cout = nb * 16 + (lane & 15);
  const float* src = Ws + (size_t)tt * 4096;
  uint32_t p[4];
#pragma unroll
  for (int j = 0; j < 4; ++j) {
    uint32_t lo = f2bf_rne(src[(kb + 2 * j) * 64 + cout]);
    uint32_t hi = f2bf_rne(src[(kb + 2 * j + 1) * 64 + cout]);
    p[j] = (hi << 16) | lo;
  }
  uint4 o;
  o.x = p[0]; o.y = p[1]; o.z = p[2]; o.w = p[3];
  Wfrag[e] = o;
}

// stage-2: reduce nblk partials -> affine (a, b') with bnrelu(x)=relu(x*a+b')
__global__ void k_stats2(const float* __restrict__ part, int nblk,
                         const float* __restrict__ gamma, const float* __restrict__ beta,
                         float* __restrict__ chanp, int cid) {
  __shared__ float s[512];
  int c = threadIdx.x & 63, q = threadIdx.x >> 6;
  float sm = 0.f, sq = 0.f;
  for (int rb = q; rb < nblk; rb += 4) {
    sm += part[rb * 128 + c];
    sq += part[rb * 128 + 64 + c];
  }
  s[threadIdx.x] = sm;
  s[256 + threadIdx.x] = sq;
  __syncthreads();
  if (q == 0) {
    sm = s[c] + s[64 + c] + s[128 + c] + s[192 + c];
    sq = s[256 + c] + s[320 + c] + s[384 + c] + s[448 + c];
    float mean = sm / (float)NROWS;
    float var = sq / (float)NROWS - mean * mean;
    float a = gamma[cid * 64 + c] * rsqrtf(var + EPSBN);
    chanp[cid * 128 + c] = a;
    chanp[cid * 128 + 64 + c] = beta[cid * 64 + c] - mean * a;
  }
}

// f0[slot] = bf16(feats[perm[slot]]) (raw, no affine) + BN-stats partials of feats
__global__ void k_cast(const float* __restrict__ feats, const int* __restrict__ perm,
                       uint4* __restrict__ f0, float* __restrict__ part) {
  __shared__ float sred[2][4][64];
  int tid = threadIdx.x, wv = tid >> 6, lane = tid & 63;
  int oct = tid & 7;
  float sm[8], sq[8];
#pragma unroll
  for (int j = 0; j < 8; j++) sm[j] = sq[j] = 0.f;
#pragma unroll 1
  for (int it = 0; it < 8; it++) {
    int g = blockIdx.x * 2048 + it * 256 + tid;
    int s = g >> 3;
    uint4 o = (uint4){0u, 0u, 0u, 0u};
    if (s < NROWS) {
      int src = perm[s];
      const float* X = feats + (size_t)src * 64 + oct * 8;
      float4 x0 = *(const float4*)X;
      float4 x1 = *(const float4*)(X + 4);
      sm[0] += x0.x; sq[0] += x0.x * x0.x;
      sm[1] += x0.y; sq[1] += x0.y * x0.y;
      sm[2] += x0.z; sq[2] += x0.z * x0.z;
      sm[3] += x0.w; sq[3] += x0.w * x0.w;
      sm[4] += x1.x; sq[4] += x1.x * x1.x;
      sm[5] += x1.y; sq[5] += x1.y * x1.y;
      sm[6] += x1.z; sq[6] += x1.z * x1.z;
      sm[7] += x1.w; sq[7] += x1.w * x1.w;
      o.x = pkbf(x0.x, x0.y);
      o.y = pkbf(x0.z, x0.w);
      o.z = pkbf(x1.x, x1.y);
      o.w = pkbf(x1.z, x1.w);
    }
    f0[g] = o;
  }
#pragma unroll
  for (int j = 0; j < 8; j++) {
    sm[j] += __shfl_xor(sm[j], 8);  sq[j] += __shfl_xor(sq[j], 8);
    sm[j] += __shfl_xor(sm[j], 16); sq[j] += __shfl_xor(sq[j], 16);
    sm[j] += __shfl_xor(sm[j], 32); sq[j] += __shfl_xor(sq[j], 32);
  }
  if (lane < 8) {
#pragma unroll
    for (int j = 0; j < 8; j++) {
      sred[0][wv][lane * 8 + j] = sm[j];
      sred[1][wv][lane * 8 + j] = sq[j];
    }
  }
  __syncthreads();
  if (tid < 64) {
    float s0 = 0.f, s1 = 0.f;
#pragma unroll
    for (int w = 0; w < 4; w++) {
      s0 += sred[0][w][tid];
      s1 += sred[1][w][tid];
    }
    part[blockIdx.x * 128 + tid] = s0;
    part[blockIdx.x * 128 + 64 + tid] = s1;
  }
}

// One tap phase: BN+ReLU+mask on A(T) in-register, 16 MFMAs, then refill
// A <- A(T+2) (addrs NIC=ni(T+2)), NIC <- ni(T+4), WC <- W(T+2). Period 2.
#define PH(T, AC, VC, WC, NIC)                                              \
  {                                                                         \
    uint4 af[2][2];                                                         \
    _Pragma("unroll") for (int rt = 0; rt < 2; rt++) {                      \
      bool vld = (VC[rt] != ZROW);                                          \
      af[rt][0] = bnrelu_frag(AC[rt][0], paL[0], paH[0], pbL[0], pbH[0], vld); \
      af[rt][1] = bnrelu_frag(AC[rt][1], paL[1], paH[1], pbL[1], pbH[1], vld); \
    }                                                                       \
    _Pragma("unroll") for (int s = 0; s < 2; s++)                           \
      _Pragma("unroll") for (int rt = 0; rt < 2; rt++)                      \
        _Pragma("unroll") for (int nb = 0; nb < 4; nb++)                    \
          acc[rt][nb] = mfma16(af[rt][s], WC[s * 4 + nb], acc[rt][nb]);     \
    _Pragma("unroll") for (int rt = 0; rt < 2; rt++) {                      \
      const uint4* hp = src + (size_t)NIC[rt] * 8 + lkg;                    \
      VC[rt] = NIC[rt];                                                     \
      AC[rt][0] = hp[0];                                                    \
      AC[rt][1] = hp[4];                                                    \
    }                                                                       \
    {                                                                       \
      int tn = (T) + 4 <= 26 ? (T) + 4 : 26;                                \
      NIC[0] = nbp[(size_t)tn * NPAD];                                      \
      NIC[1] = nbp[(size_t)tn * NPAD + 16];                                 \
    }                                                                       \
    {                                                                       \
      int tw = (T) + 2 <= 26 ? (T) + 2 : 26;                                \
      const uint4* wp = Wf + (size_t)tw * 512 + lane;                       \
      _Pragma("unroll") for (int i = 0; i < 8; i++) WC[i] = wp[i * 64];     \
    }                                                                       \
  }

// MFMA conv with fused input-BN: wave = 32 rows x 64 cout, dense 27 taps,
// bf16 gather source, XCD-chunked block swizzle. Outputs either bf16 raw
// (+res) with fused stats, or final f32 scattered to original order.
__global__ __launch_bounds__(256, 2) void k_conv(
    const uint4* __restrict__ src, const uint4* __restrict__ Wf,
    const int* __restrict__ nbr, const float* __restrict__ chanp, int cid,
    const uint4* __restrict__ resb, uint4* __restrict__ outb,
    float* __restrict__ outf, const int* __restrict__ operm,
    float* __restrict__ part, int do_stats) {
  __shared__ char smem[19456];  // slab 17408 + sred 2048
  int tid = threadIdx.x, wv = tid >> 6, lane = tid & 63;
  int bid = (int)blockIdx.x;
  int sbid = (bid & 7) * (NCBLK / 8) + (bid >> 3);  // XCD-chunked (2344%8==0)
  int tbase = (sbid * 4 + wv) * 32;
  int lrow = lane & 15, lkg = lane >> 4;

  // input-BN affine for this lane's 16 channels (2 K-halves x 8)
  const float* cp = chanp + cid * 128;
  float4 paL[2], paH[2], pbL[2], pbH[2];
#pragma unroll
  for (int s = 0; s < 2; s++) {
    paL[s] = *(const float4*)(cp + s * 32 + lkg * 8);
    paH[s] = *(const float4*)(cp + s * 32 + lkg * 8 + 4);
    pbL[s] = *(const float4*)(cp + 64 + s * 32 + lkg * 8);
    pbH[s] = *(const float4*)(cp + 64 + s * 32 + lkg * 8 + 4);
  }

  f32x4 acc[2][4];
#pragma unroll
  for (int i = 0; i < 2; i++)
#pragma unroll
    for (int j = 0; j < 4; j++) acc[i][j] = (f32x4){0.f, 0.f, 0.f, 0.f};

  const int* nbp = nbr + tbase + lrow;
  int niE[2], niO[2], vE[2], vO[2];
  uint4 aE[2][2], aO[2][2], wE[8], wO[8];
  {
    int p0[2], p1[2];
    p0[0] = nbp[0];
    p0[1] = nbp[16];
    p1[0] = nbp[NPAD];
    p1[1] = nbp[NPAD + 16];
    niE[0] = nbp[(size_t)2 * NPAD];
    niE[1] = nbp[(size_t)2 * NPAD + 16];
    niO[0] = nbp[(size_t)3 * NPAD];
    niO[1] = nbp[(size_t)3 * NPAD + 16];
#pragma unroll
    for (int rt = 0; rt < 2; rt++) {
      const uint4* hp = src + (size_t)p0[rt] * 8 + lkg;
      aE[rt][0] = hp[0];
      aE[rt][1] = hp[4];
      vE[rt] = p0[rt];
    }
#pragma unroll
    for (int rt = 0; rt < 2; rt++) {
      const uint4* hp = src + (size_t)p1[rt] * 8 + lkg;
      aO[rt][0] = hp[0];
      aO[rt][1] = hp[4];
      vO[rt] = p1[rt];
    }
    const uint4* wp = Wf + lane;
#pragma unroll
    for (int i = 0; i < 8; i++) wE[i] = wp[i * 64];
    const uint4* wq = Wf + 512 + lane;
#pragma unroll
    for (int i = 0; i < 8; i++) wO[i] = wq[i * 64];
  }

#pragma unroll 1
  for (int t = 0; t < 26; t += 2) {
    PH(t, aE, vE, wE, niE)
    PH(t + 1, aO, vO, wO, niO)
  }
  PH(26, aE, vE, wE, niE)

  // ---- epilogue: per-wave LDS transpose -> coalesced res/out + fused stats
  float sm4[4] = {0.f, 0.f, 0.f, 0.f}, sq4[4] = {0.f, 0.f, 0.f, 0.f};
  float* slab = (float*)smem + wv * 1088;  // per-wave [16][68]
  float* sred = (float*)(smem + 17408);    // [2][4][64]
#pragma unroll 1
  for (int rt = 0; rt < 2; rt++) {
#pragma unroll
    for (int nb = 0; nb < 4; nb++)
#pragma unroll
      for (int r = 0; r < 4; r++)
        slab[(lkg * 4 + r) * 68 + nb * 16 + lrow] = acc[rt][nb][r];
#pragma unroll
    for (int j = 0; j < 4; j++) {
      int row = tbase + rt * 16 + j * 4 + lkg;
      float4 vv = *(float4*)&slab[(j * 4 + lkg) * 68 + lrow * 4];
      bool live = row < NROWS;
      if (resb && live) {
        uint2 rb = *(const uint2*)((const char*)resb + (size_t)row * 128 + lrow * 8);
        vv.x += __uint_as_float(rb.x << 16);
        vv.y += __uint_as_float(rb.x & 0xFFFF0000u);
        vv.z += __uint_as_float(rb.y << 16);
        vv.w += __uint_as_float(rb.y & 0xFFFF0000u);
      }
      if (outb) {
        uint2 ob = (uint2){0u, 0u};
        if (live) {
          ob.x = pkbf(vv.x, vv.y);
          ob.y = pkbf(vv.z, vv.w);
        }
        *(uint2*)((char*)outb + (size_t)row * 128 + lrow * 8) = ob;
      }
      if (outf && live) {
        int orow = operm[row];
        *(float4*)(outf + (size_t)orow * 64 + lrow * 4) = vv;
      }
      if (live) {
        sm4[0] += vv.x; sq4[0] += vv.x * vv.x;
        sm4[1] += vv.y; sq4[1] += vv.y * vv.y;
        sm4[2] += vv.z; sq4[2] += vv.z * vv.z;
        sm4[3] += vv.w; sq4[3] += vv.w * vv.w;
      }
    }
  }
  if (do_stats) {
#pragma unroll
    for (int k = 0; k < 4; k++) {
      sm4[k] += __shfl_xor(sm4[k], 16); sq4[k] += __shfl_xor(sq4[k], 16);
      sm4[k] += __shfl_xor(sm4[k], 32); sq4[k] += __shfl_xor(sq4[k], 32);
    }
    if (lane < 16) {
#pragma unroll
      for (int k = 0; k < 4; k++) {
        sred[wv * 64 + lane * 4 + k] = sm4[k];
        sred[256 + wv * 64 + lane * 4 + k] = sq4[k];
      }
    }
    __syncthreads();
    if (tid < 64) {
      float s0 = 0.f, s1 = 0.f;
#pragma unroll
      for (int w = 0; w < 4; w++) {
        s0 += sred[w * 64 + tid];
        s1 += sred[256 + w * 64 + tid];
      }
      part[bid * 128 + tid] = s0;
      part[bid * 128 + 64 + tid] = s1;
    }
  }
}

extern "C" void kernel_launch(void* const* d_in, const int* in_sizes, int n_in,
                              void* d_out, int out_size, void* d_ws, size_t ws_size,
                              hipStream_t stream) {
  const float* feats = (const float*)d_in[0];
  const float* Ws = (const float*)d_in[1];
  const float* gammas = (const float*)d_in[2];
  const float* betas = (const float*)d_in[3];
  const int* pos = (const int*)d_in[4];
  float* out = (float*)d_out;

  char* w = (char*)d_ws;
  auto alloc = [&](size_t b) {
    char* p = w;
    w += (b + 255) & ~(size_t)255;
    return p;
  };
  int* nbr = (int*)alloc((size_t)27 * NPAD * 4);           // 32.4 MB
  uint4* Wfrag = (uint4*)alloc((size_t)4 * 27 * 512 * 16); // 0.9 MB
  float* part = (float*)alloc((size_t)NCBLK * 128 * 4);    // 1.2 MB
  float* chanp = (float*)alloc((size_t)4 * 128 * 4);       // 2 KB
  int* perm = (int*)alloc((size_t)NPAD * 4);               // 1.2 MB
  int* iperm = (int*)alloc((size_t)NROWS * 4);             // 1.2 MB
  int* ccnt = (int*)alloc((size_t)NCELLS * 4);             // 32 KB
  int* cfill = (int*)alloc((size_t)NCELLS * 4);            // 32 KB
  int* cstart = (int*)alloc((size_t)NCELLS * 4);           // 32 KB
  uint4* f0 = (uint4*)alloc((size_t)NPAD * 128);           // 38.4 MB bf16
  uint4* x1 = (uint4*)alloc((size_t)NPAD * 128);           // 38.4 MB bf16
  char* reg0 = alloc((size_t)NPAD * 128);                  // 38.4 MB
  uint4* c1 = (uint4*)reg0;                                // conv raw bf16
  int* lut = (int*)reg0;  // lut (16.8 MB) dead before c1 first written

  hipMemsetAsync(lut, 0xFF, (size_t)NBATCH * D3 * 4, stream);
  hipMemsetAsync(ccnt, 0, (size_t)NCELLS * 8, stream);  // ccnt + cfill adjacent
  int gpts = (NROWS + 255) / 256;
  k_scatter<<<gpts, 256, 0, stream>>>(pos, lut);
  k_cellcount<<<gpts, 256, 0, stream>>>(pos, ccnt);
  k_scan<<<1, 1024, 0, stream>>>(ccnt, cstart);
  k_bucket<<<gpts, 256, 0, stream>>>(pos, cstart, cfill, perm, iperm);
  k_nbr_s<<<NPAD / 256, 256, 0, stream>>>(pos, lut, perm, iperm, nbr);
  k_wpack<<<216, 256, 0, stream>>>(Ws, Wfrag);

  k_cast<<<1172, 256, 0, stream>>>(feats, perm, f0, part);
  k_stats2<<<1, 256, 0, stream>>>(part, 1172, gammas, betas, chanp, 0);

  k_conv<<<NCBLK, 256, 0, stream>>>(f0, Wfrag + 0 * 27 * 512, nbr, chanp, 0,
                                    nullptr, c1, nullptr, nullptr, part, 1);
  k_stats2<<<1, 256, 0, stream>>>(part, NCBLK, gammas, betas, chanp, 1);

  k_conv<<<NCBLK, 256, 0, stream>>>(c1, Wfrag + 1 * 27 * 512, nbr, chanp, 1,
                                    f0, x1, nullptr, nullptr, part, 1);
  k_stats2<<<1, 256, 0, stream>>>(part, NCBLK, gammas, betas, chanp, 2);

  k_conv<<<NCBLK, 256, 0, stream>>>(x1, Wfrag + 2 * 27 * 512, nbr, chanp, 2,
                                    nullptr, c1, nullptr, nullptr, part, 1);
  k_stats2<<<1, 256, 0, stream>>>(part, NCBLK, gammas, betas, chanp, 3);

  k_conv<<<NCBLK, 256, 0, stream>>>(c1, Wfrag + 3 * 27 * 512, nbr, chanp, 3,
                                    x1, nullptr, out, perm, part, 0);
}

// Round 10
// 1233.507 us; speedup vs baseline: 1.4093x; 1.0419x over previous
//
#include <hip/hip_runtime.h>
#include <stdint.h>

#define DGRID 128
#define D3 (DGRID * DGRID * DGRID)
#define NBATCH 2
#define NPTS 150000
#define NROWS (NBATCH * NPTS)
#define NPAD 300032            // ceil(NROWS/64)*64
#define ZROW NROWS             // dedicated all-zero row (sorted space)
#define NCBLK (NPAD / 128)     // 2344 conv blocks (4 waves x 32 rows); %8==0
#define NCELLS 8192            // 2 batches x 16^3 macro-cells (8^3 voxels each)
#define EPSBN 1e-4f

typedef __attribute__((ext_vector_type(8))) short s16x8;
typedef __attribute__((ext_vector_type(4))) float f32x4;

static __device__ __forceinline__ uint32_t f2bf_rne(float f) {
  uint32_t b = __float_as_uint(f);
  return (b + 0x7FFFu + ((b >> 16) & 1u)) >> 16;
}

static __device__ __forceinline__ uint32_t pkbf(float lo, float hi) {
  uint32_t r;
  asm("v_cvt_pk_bf16_f32 %0, %1, %2" : "=v"(r) : "v"(lo), "v"(hi));
  return r;
}

static __device__ __forceinline__ f32x4 mfma16(uint4 a, uint4 b, f32x4 c) {
  return __builtin_amdgcn_mfma_f32_16x16x32_bf16(
      __builtin_bit_cast(s16x8, a), __builtin_bit_cast(s16x8, b), c, 0, 0, 0);
}

// BN+ReLU on 8 bf16 channels packed in a uint4
static __device__ __forceinline__ uint4 bnrelu_frag(uint4 u, float4 aL, float4 aH,
                                                    float4 bL, float4 bH) {
  float y0, y1;
  uint4 o;
  y0 = fmaxf(fmaf(__uint_as_float(u.x << 16), aL.x, bL.x), 0.f);
  y1 = fmaxf(fmaf(__uint_as_float(u.x & 0xFFFF0000u), aL.y, bL.y), 0.f);
  o.x = pkbf(y0, y1);
  y0 = fmaxf(fmaf(__uint_as_float(u.y << 16), aL.z, bL.z), 0.f);
  y1 = fmaxf(fmaf(__uint_as_float(u.y & 0xFFFF0000u), aL.w, bL.w), 0.f);
  o.y = pkbf(y0, y1);
  y0 = fmaxf(fmaf(__uint_as_float(u.z << 16), aH.x, bH.x), 0.f);
  y1 = fmaxf(fmaf(__uint_as_float(u.z & 0xFFFF0000u), aH.y, bH.y), 0.f);
  o.z = pkbf(y0, y1);
  y0 = fmaxf(fmaf(__uint_as_float(u.w << 16), aH.z, bH.z), 0.f);
  y1 = fmaxf(fmaf(__uint_as_float(u.w & 0xFFFF0000u), aH.w, bH.w), 0.f);
  o.w = pkbf(y0, y1);
  return o;
}

// ---------- geometry prep ----------
__global__ void k_scatter(const int* __restrict__ pos, int* __restrict__ lut) {
  int g = blockIdx.x * blockDim.x + threadIdx.x;
  if (g >= NROWS) return;
  int b = g / NPTS;
  int i = g - b * NPTS;
  lut[(size_t)b * D3 + (pos[3 * g] * DGRID + pos[3 * g + 1]) * DGRID + pos[3 * g + 2]] = i;
}

__global__ void k_cellcount(const int* __restrict__ pos, int* __restrict__ cnt) {
  int g = blockIdx.x * blockDim.x + threadIdx.x;
  if (g >= NROWS) return;
  int b = g / NPTS;
  int cid = (b << 12) | ((pos[3 * g] >> 3) << 8) | ((pos[3 * g + 1] >> 3) << 4) |
            (pos[3 * g + 2] >> 3);
  atomicAdd(&cnt[cid], 1);
}

__global__ void k_scan(const int* __restrict__ cnt, int* __restrict__ cstart) {
  __shared__ int s[1024];
  int tid = threadIdx.x;
  int e[8];
  int sum = 0;
#pragma unroll
  for (int j = 0; j < 8; j++) {
    int v = cnt[tid * 8 + j];
    e[j] = sum;
    sum += v;
  }
  s[tid] = sum;
  __syncthreads();
  for (int off = 1; off < 1024; off <<= 1) {
    int t = (tid >= off) ? s[tid - off] : 0;
    __syncthreads();
    s[tid] += t;
    __syncthreads();
  }
  int base = tid ? s[tid - 1] : 0;
#pragma unroll
  for (int j = 0; j < 8; j++) cstart[tid * 8 + j] = base + e[j];
}

__global__ void k_bucket(const int* __restrict__ pos, const int* __restrict__ cstart,
                         int* __restrict__ fill, int* __restrict__ perm,
                         int* __restrict__ iperm) {
  int g = blockIdx.x * blockDim.x + threadIdx.x;
  if (g >= NROWS) return;
  int b = g / NPTS;
  int cid = (b << 12) | ((pos[3 * g] >> 3) << 8) | ((pos[3 * g + 1] >> 3) << 4) |
            (pos[3 * g + 2] >> 3);
  int slot = cstart[cid] + atomicAdd(&fill[cid], 1);
  perm[slot] = g;
  iperm[g] = slot;
}

__global__ void k_nbr_s(const int* __restrict__ pos, const int* __restrict__ lut,
                        const int* __restrict__ perm, const int* __restrict__ iperm,
                        int* __restrict__ nbr) {
  int s = blockIdx.x * blockDim.x + threadIdx.x;
  if (s >= NPAD) return;
  if (s >= NROWS) {
#pragma unroll
    for (int t = 0; t < 27; ++t) nbr[(size_t)t * NPAD + s] = ZROW;
    return;
  }
  int g = perm[s];
  int b = g / NPTS;
  int x = pos[3 * g], y = pos[3 * g + 1], z = pos[3 * g + 2];
  const int* L = lut + (size_t)b * D3;
  const int* ip = iperm + (size_t)b * NPTS;
#pragma unroll
  for (int t = 0; t < 27; ++t) {
    int nx = x + t / 9 - 1;
    int ny = y + (t / 3) % 3 - 1;
    int nz = z + t % 3 - 1;
    int v = ZROW;
    if ((unsigned)nx < DGRID && (unsigned)ny < DGRID && (unsigned)nz < DGRID) {
      int n = L[(nx * DGRID + ny) * DGRID + nz];
      if (n >= 0) v = ip[n];
    }
    nbr[(size_t)t * NPAD + s] = v;
  }
}

__global__ void k_wpack(const float* __restrict__ Ws, uint4* __restrict__ Wfrag) {
  int e = blockIdx.x * 256 + threadIdx.x;
  if (e >= 4 * 27 * 512) return;
  int lane = e & 63, nb = (e >> 6) & 3, s = (e >> 8) & 1, tt = e >> 9;
  int kb = s * 32 + (lane >> 4) * 8;
  int cout = nb * 16 + (lane & 15);
  const float* src = Ws + (size_t)tt * 4096;
  uint32_t p[4];
#pragma unroll
  for (int j = 0; j < 4; ++j) {
    uint32_t lo = f2bf_rne(src[(kb + 2 * j) * 64 + cout]);
    uint32_t hi = f2bf_rne(src[(kb + 2 * j + 1) * 64 + cout]);
    p[j] = (hi << 16) | lo;
  }
  uint4 o;
  o.x = p[0]; o.y = p[1]; o.z = p[2]; o.w = p[3];
  Wfrag[e] = o;
}

// stage-2: reduce nblk partials -> affine (a, b') with bnrelu(x)=relu(x*a+b')
__global__ void k_stats2(const float* __restrict__ part, int nblk,
                         const float* __restrict__ gamma, const float* __restrict__ beta,
                         float* __restrict__ chanp, int cid) {
  __shared__ float s[512];
  int c = threadIdx.x & 63, q = threadIdx.x >> 6;
  float sm = 0.f, sq = 0.f;
  for (int rb = q; rb < nblk; rb += 4) {
    sm += part[rb * 128 + c];
    sq += part[rb * 128 + 64 + c];
  }
  s[threadIdx.x] = sm;
  s[256 + threadIdx.x] = sq;
  __syncthreads();
  if (q == 0) {
    sm = s[c] + s[64 + c] + s[128 + c] + s[192 + c];
    sq = s[256 + c] + s[320 + c] + s[384 + c] + s[448 + c];
    float mean = sm / (float)NROWS;
    float var = sq / (float)NROWS - mean * mean;
    float a = gamma[cid * 64 + c] * rsqrtf(var + EPSBN);
    chanp[cid * 128 + c] = a;
    chanp[cid * 128 + 64 + c] = beta[cid * 64 + c] - mean * a;
  }
}

// f0[slot] = bf16(feats[perm[slot]]) + BN-stats partials of feats
__global__ void k_cast(const float* __restrict__ feats, const int* __restrict__ perm,
                       uint4* __restrict__ f0, float* __restrict__ part) {
  __shared__ float sred[2][4][64];
  int tid = threadIdx.x, wv = tid >> 6, lane = tid & 63;
  int oct = tid & 7;
  float sm[8], sq[8];
#pragma unroll
  for (int j = 0; j < 8; j++) sm[j] = sq[j] = 0.f;
#pragma unroll 1
  for (int it = 0; it < 8; it++) {
    int g = blockIdx.x * 2048 + it * 256 + tid;
    int s = g >> 3;
    uint4 o = (uint4){0u, 0u, 0u, 0u};
    if (s < NROWS) {
      int src = perm[s];
      const float* X = feats + (size_t)src * 64 + oct * 8;
      float4 x0 = *(const float4*)X;
      float4 x1 = *(const float4*)(X + 4);
      sm[0] += x0.x; sq[0] += x0.x * x0.x;
      sm[1] += x0.y; sq[1] += x0.y * x0.y;
      sm[2] += x0.z; sq[2] += x0.z * x0.z;
      sm[3] += x0.w; sq[3] += x0.w * x0.w;
      sm[4] += x1.x; sq[4] += x1.x * x1.x;
      sm[5] += x1.y; sq[5] += x1.y * x1.y;
      sm[6] += x1.z; sq[6] += x1.z * x1.z;
      sm[7] += x1.w; sq[7] += x1.w * x1.w;
      o.x = pkbf(x0.x, x0.y);
      o.y = pkbf(x0.z, x0.w);
      o.z = pkbf(x1.x, x1.y);
      o.w = pkbf(x1.z, x1.w);
    }
    f0[g] = o;
  }
#pragma unroll
  for (int j = 0; j < 8; j++) {
    sm[j] += __shfl_xor(sm[j], 8);  sq[j] += __shfl_xor(sq[j], 8);
    sm[j] += __shfl_xor(sm[j], 16); sq[j] += __shfl_xor(sq[j], 16);
    sm[j] += __shfl_xor(sm[j], 32); sq[j] += __shfl_xor(sq[j], 32);
  }
  if (lane < 8) {
#pragma unroll
    for (int j = 0; j < 8; j++) {
      sred[0][wv][lane * 8 + j] = sm[j];
      sred[1][wv][lane * 8 + j] = sq[j];
    }
  }
  __syncthreads();
  if (tid < 64) {
    float s0 = 0.f, s1 = 0.f;
#pragma unroll
    for (int w = 0; w < 4; w++) {
      s0 += sred[0][w][tid];
      s1 += sred[1][w][tid];
    }
    part[blockIdx.x * 128 + tid] = s0;
    part[blockIdx.x * 128 + 64 + tid] = s1;
  }
}

// h[g] = bnrelu(x[g]) bf16->bf16 linear; rows >= NROWS (incl ZROW) -> zeros
__global__ void k_hb(const uint4* __restrict__ x, const float* __restrict__ chanp,
                     int cid, uint4* __restrict__ h) {
  int tid = threadIdx.x;
  int c0 = (tid & 7) * 8;
  const float* cp = chanp + cid * 128;
  float4 aL = *(const float4*)(cp + c0);
  float4 aH = *(const float4*)(cp + c0 + 4);
  float4 bL = *(const float4*)(cp + 64 + c0);
  float4 bH = *(const float4*)(cp + 64 + c0 + 4);
#pragma unroll 1
  for (int it = 0; it < 8; it++) {
    int g = blockIdx.x * 2048 + it * 256 + tid;
    int row = g >> 3;
    uint4 o = (uint4){0u, 0u, 0u, 0u};
    if (row < NROWS) o = bnrelu_frag(x[g], aL, aH, bL, bH);
    h[g] = o;
  }
}

// One tap phase: 16 MFMAs on AC x wb, then refill AC <- A(T+2) (addrs NIC),
// NIC <- ni(T+4), wb <- W(T+1). Single W buffer, A/ni ping-pong depth 2.
#define PH(T, AC, NIC)                                                      \
  {                                                                         \
    _Pragma("unroll") for (int s = 0; s < 2; s++)                           \
      _Pragma("unroll") for (int rt = 0; rt < 2; rt++)                      \
        _Pragma("unroll") for (int nb = 0; nb < 4; nb++)                    \
          acc[rt][nb] = mfma16(AC[rt][s], wb[s * 4 + nb], acc[rt][nb]);     \
    _Pragma("unroll") for (int rt = 0; rt < 2; rt++) {                      \
      const uint4* hp = src + (size_t)NIC[rt] * 8 + lkg;                    \
      AC[rt][0] = hp[0];                                                    \
      AC[rt][1] = hp[4];                                                    \
    }                                                                       \
    {                                                                       \
      int tn = (T) + 4 <= 26 ? (T) + 4 : 26;                                \
      NIC[0] = nbp[(size_t)tn * NPAD];                                      \
      NIC[1] = nbp[(size_t)tn * NPAD + 16];                                 \
    }                                                                       \
    {                                                                       \
      int tw = (T) + 1 <= 26 ? (T) + 1 : 26;                                \
      const uint4* wp = Wf + (size_t)tw * 512 + lane;                       \
      _Pragma("unroll") for (int i = 0; i < 8; i++) wb[i] = wp[i * 64];     \
    }                                                                       \
  }

// MFMA conv, minimal state: wave = 32 rows x 64 cout, dense 27 taps, zero-row
// gathers from pre-BN'd bf16 h; acc32 + A32 + W32 + ni4 regs. XCD swizzle.
__global__ __launch_bounds__(256) void k_conv(
    const uint4* __restrict__ src, const uint4* __restrict__ Wf,
    const int* __restrict__ nbr,
    const uint4* __restrict__ resb, uint4* __restrict__ outb,
    float* __restrict__ outf, const int* __restrict__ operm,
    float* __restrict__ part, int do_stats) {
  __shared__ char smem[19456];  // slab 17408 + sred 2048
  int tid = threadIdx.x, wv = tid >> 6, lane = tid & 63;
  int bid = (int)blockIdx.x;
  int sbid = (bid & 7) * (NCBLK / 8) + (bid >> 3);  // XCD-chunked (2344%8==0)
  int tbase = (sbid * 4 + wv) * 32;
  int lrow = lane & 15, lkg = lane >> 4;

  f32x4 acc[2][4];
#pragma unroll
  for (int i = 0; i < 2; i++)
#pragma unroll
    for (int j = 0; j < 4; j++) acc[i][j] = (f32x4){0.f, 0.f, 0.f, 0.f};

  const int* nbp = nbr + tbase + lrow;
  int niE[2], niO[2];
  uint4 aE[2][2], aO[2][2], wb[8];
  {
    int p0[2], p1[2];
    p0[0] = nbp[0];
    p0[1] = nbp[16];
    p1[0] = nbp[NPAD];
    p1[1] = nbp[NPAD + 16];
    niE[0] = nbp[(size_t)2 * NPAD];
    niE[1] = nbp[(size_t)2 * NPAD + 16];
    niO[0] = nbp[(size_t)3 * NPAD];
    niO[1] = nbp[(size_t)3 * NPAD + 16];
#pragma unroll
    for (int rt = 0; rt < 2; rt++) {
      const uint4* hp = src + (size_t)p0[rt] * 8 + lkg;
      aE[rt][0] = hp[0];
      aE[rt][1] = hp[4];
    }
#pragma unroll
    for (int rt = 0; rt < 2; rt++) {
      const uint4* hp = src + (size_t)p1[rt] * 8 + lkg;
      aO[rt][0] = hp[0];
      aO[rt][1] = hp[4];
    }
    const uint4* wp = Wf + lane;
#pragma unroll
    for (int i = 0; i < 8; i++) wb[i] = wp[i * 64];
  }

#pragma unroll 1
  for (int t = 0; t < 26; t += 2) {
    PH(t, aE, niE)
    PH(t + 1, aO, niO)
  }
  PH(26, aE, niE)

  // ---- epilogue: per-wave LDS transpose -> coalesced res/out + fused stats
  float sm4[4] = {0.f, 0.f, 0.f, 0.f}, sq4[4] = {0.f, 0.f, 0.f, 0.f};
  float* slab = (float*)smem + wv * 1088;  // per-wave [16][68]
  float* sred = (float*)(smem + 17408);    // [2][4][64]
#pragma unroll 1
  for (int rt = 0; rt < 2; rt++) {
#pragma unroll
    for (int nb = 0; nb < 4; nb++)
#pragma unroll
      for (int r = 0; r < 4; r++)
        slab[(lkg * 4 + r) * 68 + nb * 16 + lrow] = acc[rt][nb][r];
#pragma unroll
    for (int j = 0; j < 4; j++) {
      int row = tbase + rt * 16 + j * 4 + lkg;
      float4 vv = *(float4*)&slab[(j * 4 + lkg) * 68 + lrow * 4];
      bool live = row < NROWS;
      if (resb && live) {
        uint2 rb = *(const uint2*)((const char*)resb + (size_t)row * 128 + lrow * 8);
        vv.x += __uint_as_float(rb.x << 16);
        vv.y += __uint_as_float(rb.x & 0xFFFF0000u);
        vv.z += __uint_as_float(rb.y << 16);
        vv.w += __uint_as_float(rb.y & 0xFFFF0000u);
      }
      if (outb) {
        uint2 ob = (uint2){0u, 0u};
        if (live) {
          ob.x = pkbf(vv.x, vv.y);
          ob.y = pkbf(vv.z, vv.w);
        }
        *(uint2*)((char*)outb + (size_t)row * 128 + lrow * 8) = ob;
      }
      if (outf && live) {
        int orow = operm[row];
        *(float4*)(outf + (size_t)orow * 64 + lrow * 4) = vv;
      }
      if (live) {
        sm4[0] += vv.x; sq4[0] += vv.x * vv.x;
        sm4[1] += vv.y; sq4[1] += vv.y * vv.y;
        sm4[2] += vv.z; sq4[2] += vv.z * vv.z;
        sm4[3] += vv.w; sq4[3] += vv.w * vv.w;
      }
    }
  }
  if (do_stats) {
#pragma unroll
    for (int k = 0; k < 4; k++) {
      sm4[k] += __shfl_xor(sm4[k], 16); sq4[k] += __shfl_xor(sq4[k], 16);
      sm4[k] += __shfl_xor(sm4[k], 32); sq4[k] += __shfl_xor(sq4[k], 32);
    }
    if (lane < 16) {
#pragma unroll
      for (int k = 0; k < 4; k++) {
        sred[wv * 64 + lane * 4 + k] = sm4[k];
        sred[256 + wv * 64 + lane * 4 + k] = sq4[k];
      }
    }
    __syncthreads();
    if (tid < 64) {
      float s0 = 0.f, s1 = 0.f;
#pragma unroll
      for (int w = 0; w < 4; w++) {
        s0 += sred[w * 64 + tid];
        s1 += sred[256 + w * 64 + tid];
      }
      part[bid * 128 + tid] = s0;
      part[bid * 128 + 64 + tid] = s1;
    }
  }
}

extern "C" void kernel_launch(void* const* d_in, const int* in_sizes, int n_in,
                              void* d_out, int out_size, void* d_ws, size_t ws_size,
                              hipStream_t stream) {
  const float* feats = (const float*)d_in[0];
  const float* Ws = (const float*)d_in[1];
  const float* gammas = (const float*)d_in[2];
  const float* betas = (const float*)d_in[3];
  const int* pos = (const int*)d_in[4];
  float* out = (float*)d_out;

  char* w = (char*)d_ws;
  auto alloc = [&](size_t b) {
    char* p = w;
    w += (b + 255) & ~(size_t)255;
    return p;
  };
  int* nbr = (int*)alloc((size_t)27 * NPAD * 4);           // 32.4 MB
  uint4* Wfrag = (uint4*)alloc((size_t)4 * 27 * 512 * 16); // 0.9 MB
  float* part = (float*)alloc((size_t)NCBLK * 128 * 4);    // 1.2 MB
  float* chanp = (float*)alloc((size_t)4 * 128 * 4);       // 2 KB
  int* perm = (int*)alloc((size_t)NPAD * 4);               // 1.2 MB
  int* iperm = (int*)alloc((size_t)NROWS * 4);             // 1.2 MB
  int* ccnt = (int*)alloc((size_t)NCELLS * 4);             // 32 KB
  int* cfill = (int*)alloc((size_t)NCELLS * 4);            // 32 KB
  int* cstart = (int*)alloc((size_t)NCELLS * 4);           // 32 KB
  uint4* f0 = (uint4*)alloc((size_t)NPAD * 128);           // 38.4 MB bf16
  uint4* x1 = (uint4*)alloc((size_t)NPAD * 128);           // 38.4 MB bf16
  uint4* h = (uint4*)alloc((size_t)NPAD * 128);            // 38.4 MB bf16
  char* reg0 = alloc((size_t)NPAD * 128);                  // 38.4 MB
  uint4* c1 = (uint4*)reg0;                                // conv raw bf16
  int* lut = (int*)reg0;  // lut (16.8 MB) dead before c1 first written

  hipMemsetAsync(lut, 0xFF, (size_t)NBATCH * D3 * 4, stream);
  hipMemsetAsync(ccnt, 0, (size_t)NCELLS * 8, stream);  // ccnt + cfill adjacent
  int gpts = (NROWS + 255) / 256;
  k_scatter<<<gpts, 256, 0, stream>>>(pos, lut);
  k_cellcount<<<gpts, 256, 0, stream>>>(pos, ccnt);
  k_scan<<<1, 1024, 0, stream>>>(ccnt, cstart);
  k_bucket<<<gpts, 256, 0, stream>>>(pos, cstart, cfill, perm, iperm);
  k_nbr_s<<<NPAD / 256, 256, 0, stream>>>(pos, lut, perm, iperm, nbr);
  k_wpack<<<216, 256, 0, stream>>>(Ws, Wfrag);

  k_cast<<<1172, 256, 0, stream>>>(feats, perm, f0, part);
  k_stats2<<<1, 256, 0, stream>>>(part, 1172, gammas, betas, chanp, 0);
  k_hb<<<1172, 256, 0, stream>>>(f0, chanp, 0, h);
  k_conv<<<NCBLK, 256, 0, stream>>>(h, Wfrag + 0 * 27 * 512, nbr,
                                    nullptr, c1, nullptr, nullptr, part, 1);

  k_stats2<<<1, 256, 0, stream>>>(part, NCBLK, gammas, betas, chanp, 1);
  k_hb<<<1172, 256, 0, stream>>>(c1, chanp, 1, h);
  k_conv<<<NCBLK, 256, 0, stream>>>(h, Wfrag + 1 * 27 * 512, nbr,
                                    f0, x1, nullptr, nullptr, part, 1);

  k_stats2<<<1, 256, 0, stream>>>(part, NCBLK, gammas, betas, chanp, 2);
  k_hb<<<1172, 256, 0, stream>>>(x1, chanp, 2, h);
  k_conv<<<NCBLK, 256, 0, stream>>>(h, Wfrag + 2 * 27 * 512, nbr,
                                    nullptr, c1, nullptr, nullptr, part, 1);

  k_stats2<<<1, 256, 0, stream>>>(part, NCBLK, gammas, betas, chanp, 3);
  k_hb<<<1172, 256, 0, stream>>>(c1, chanp, 3, h);
  k_conv<<<NCBLK, 256, 0, stream>>>(h, Wfrag + 3 * 27 * 512, nbr,
                                    x1, nullptr, out, perm, part, 0);
}